// Round 7
// baseline (515.788 us; speedup 1.0000x reference)
//
#include <hip/hip_runtime.h>

#define HASH_SIZE 16384
#define N_LEVELS  12
#define LP        6   // level pairs per point
#define NSTAGED   6   // levels 0..5 live in LDS (tables: 17+33+65+129+257+513 = 1014 float4)
#define LDS_TOT   1014

// native 4-float vector: accepted by __builtin_nontemporal_store, same
// 16B layout as float4, lowers to global_store_dwordx4 nt
typedef float floatx4 __attribute__((ext_vector_type(4)));

// ---------------------------------------------------------------------------
// Kernel A: build paired, level-major gather table in workspace (3 MB, L2-fit).
//   ws4[l*HASH_SIZE + h] = { e0.x, e0.y, e1.x, e1.y } with h1=(h+1)&mask baked.
// ---------------------------------------------------------------------------
__global__ __launch_bounds__(256) void build_ws_kernel(
    const float* __restrict__ table,   // [HASH_SIZE, N_LEVELS*2]
    float4* __restrict__ ws4)          // [N_LEVELS * HASH_SIZE]
{
    int tid = blockIdx.x * blockDim.x + threadIdx.x;
    if (tid >= N_LEVELS * HASH_SIZE) return;
    int l  = tid >> 14;
    int h  = tid & (HASH_SIZE - 1);
    int h1 = (h + 1) & (HASH_SIZE - 1);
    const float2 e0 = *reinterpret_cast<const float2*>(table + h  * (N_LEVELS * 2) + l * 2);
    const float2 e1 = *reinterpret_cast<const float2*>(table + h1 * (N_LEVELS * 2) + l * 2);
    ws4[tid] = make_float4(e0.x, e0.y, e1.x, e1.y);
}

// ---------------------------------------------------------------------------
// Kernel B: grid-stride, thread-per-(point, level-pair).
//   stride % 6 == 0  ->  p is constant per thread; b += stride/6 per iter.
//   Levels 0..5: LDS gather (16.2 KB staged once per block).
//   Levels 6..11: global float4 gather from L2-resident ws4.
//   Output: one nontemporal float4 store per iter (keeps ws4 in L2).
// ---------------------------------------------------------------------------
__global__ __launch_bounds__(256) void hashgrid_main_kernel(
    const float* __restrict__ x,
    const float4* __restrict__ ws4,
    float* __restrict__ out,           // [BATCH*24] floats; we store 16B chunks
    int total)                         // BATCH * 6
{
    __shared__ float4 lds[LDS_TOT];

    // stage levels 0..5; compile-time offsets so no dynamic-indexed local array
    #pragma unroll
    for (int l = 0; l < NSTAGED; ++l) {
        const int off = (l == 0) ? 0 : (l == 1) ? 17 : (l == 2) ? 50
                      : (l == 3) ? 115 : (l == 4) ? 244 : 501;
        const int n   = (16 << l) + 1;
        for (int h = threadIdx.x; h < n; h += 256)
            lds[off + h] = ws4[l * HASH_SIZE + h];
    }
    __syncthreads();

    const int stride = gridDim.x * 256;          // launch guarantees stride % 6 == 0
    int t = blockIdx.x * 256 + threadIdx.x;
    int b = t / LP;
    const int p = t - b * LP;                    // constant across iterations
    const int bstep = stride / LP;

    const int   l0 = 2 * p, l1 = 2 * p + 1;
    const float res0 = (float)(16 << l0);
    const float res1 = (float)(16 << l1);
    const bool  inLds = (p < 3);
    // LDS offsets for staged levels (select chain -> no scratch array)
    const int lo0 = (p == 0) ? 0  : (p == 1) ? 50  : 244;
    const int lo1 = (p == 0) ? 17 : (p == 1) ? 115 : 501;
    const float4* g0 = ws4 + l0 * HASH_SIZE;
    const float4* g1 = ws4 + l1 * HASH_SIZE;

    #pragma unroll 2
    for (; t < total; t += stride, b += bstep) {
        float xc = fminf(fmaxf(x[b], 0.0f), 1.0f);
        float p0 = xc * res0, p1 = xc * res1;
        float f0 = floorf(p0), f1 = floorf(p1);
        float w0 = p0 - f0,    w1 = p1 - f1;
        int   h0 = (int)f0,    h1 = (int)f1;

        float4 e0, e1;
        if (inLds) {
            e0 = lds[lo0 + h0];                  // h0 <= res0 < staged size
            e1 = lds[lo1 + h1];
        } else {
            e0 = g0[h0 & (HASH_SIZE - 1)];
            e1 = g1[h1 & (HASH_SIZE - 1)];
        }

        floatx4 r;
        r.x = (1.0f - w0) * e0.x + w0 * e0.z;
        r.y = (1.0f - w0) * e0.y + w0 * e0.w;
        r.z = (1.0f - w1) * e1.x + w1 * e1.z;
        r.w = (1.0f - w1) * e1.y + w1 * e1.w;

        __builtin_nontemporal_store(r, reinterpret_cast<floatx4*>(out) + t);
    }
}

// ---------------------------------------------------------------------------
// Fallback (ws too small): round-2 direct kernel, known-correct.
// ---------------------------------------------------------------------------
__global__ __launch_bounds__(256) void hashgrid_direct_kernel(
    const float* __restrict__ x,
    const float* __restrict__ table,
    float* __restrict__ out,
    int total)
{
    int idx = blockIdx.x * blockDim.x + threadIdx.x;
    if (idx >= total) return;
    int b = idx / N_LEVELS;
    int l = idx - b * N_LEVELS;
    float xc  = fminf(fmaxf(x[b], 0.0f), 1.0f);
    float res = (float)(16 << l);
    float pos = xc * res;
    float fi  = floorf(pos);
    int   i0  = (int)fi;
    float w   = pos - fi;
    int h0 = i0 & (HASH_SIZE - 1);
    int h1 = (i0 + 1) & (HASH_SIZE - 1);
    const float2 e0 = *reinterpret_cast<const float2*>(table + h0 * (N_LEVELS * 2) + l * 2);
    const float2 e1 = *reinterpret_cast<const float2*>(table + h1 * (N_LEVELS * 2) + l * 2);
    float omw = 1.0f - w;
    float2 rr;
    rr.x = omw * e0.x + w * e1.x;
    rr.y = omw * e0.y + w * e1.y;
    *reinterpret_cast<float2*>(out + (size_t)idx * 2) = rr;
}

extern "C" void kernel_launch(void* const* d_in, const int* in_sizes, int n_in,
                              void* d_out, int out_size, void* d_ws, size_t ws_size,
                              hipStream_t stream) {
    const float* x     = (const float*)d_in[0];
    const float* table = (const float*)d_in[1];
    int batch = in_sizes[0];

    const size_t ws_needed = (size_t)N_LEVELS * HASH_SIZE * sizeof(float4);  // 3 MB

    if (ws_size >= ws_needed) {
        float4* ws4 = (float4*)d_ws;

        int ta = N_LEVELS * HASH_SIZE;
        build_ws_kernel<<<(ta + 255) / 256, 256, 0, stream>>>(table, ws4);

        int total = batch * LP;                   // BATCH * 6
        // grid*256 must be divisible by 6 -> 3072*256 = 786432 = 6*131072;
        // 25165824 / 786432 = 32 exact iterations, no tail.
        int grid = 3072;
        hashgrid_main_kernel<<<grid, 256, 0, stream>>>(
            x, ws4, (float*)d_out, total);
    } else {
        int total = batch * N_LEVELS;
        hashgrid_direct_kernel<<<(total + 255) / 256, 256, 0, stream>>>(
            x, table, (float*)d_out, total);
    }
}

// Round 8
// 489.017 us; speedup vs baseline: 1.0547x; 1.0547x over previous
//
#include <hip/hip_runtime.h>

#define HASH_SIZE 16384
#define N_LEVELS  12
#define LP        6   // level pairs per point

typedef float floatx4 __attribute__((ext_vector_type(4)));

// ---------------------------------------------------------------------------
// Kernel A: build paired, level-major gather table in workspace (3 MB, L2-fit).
//   ws4[l*HASH_SIZE + h] = { e0.x, e0.y, e1.x, e1.y } with h1=(h+1)&mask baked.
// ---------------------------------------------------------------------------
__global__ __launch_bounds__(256) void build_ws_kernel(
    const float* __restrict__ table,   // [HASH_SIZE, N_LEVELS*2]
    float4* __restrict__ ws4)          // [N_LEVELS * HASH_SIZE]
{
    int tid = blockIdx.x * blockDim.x + threadIdx.x;
    if (tid >= N_LEVELS * HASH_SIZE) return;
    int l  = tid >> 14;
    int h  = tid & (HASH_SIZE - 1);
    int h1 = (h + 1) & (HASH_SIZE - 1);
    const float2 e0 = *reinterpret_cast<const float2*>(table + h  * (N_LEVELS * 2) + l * 2);
    const float2 e1 = *reinterpret_cast<const float2*>(table + h1 * (N_LEVELS * 2) + l * 2);
    ws4[tid] = make_float4(e0.x, e0.y, e1.x, e1.y);
}

// ---------------------------------------------------------------------------
// Kernel B: one thread per (level-pair, 4 points).
//   t in [0, quarter); handles outputs t, t+quarter, t+2q, t+3q (same p).
//   All 8 scattered gathers issued before any interpolation -> 4x the
//   per-wave outstanding line-misses vs round-5 (MSHR/latency-bound model).
// ---------------------------------------------------------------------------
__global__ __launch_bounds__(256) void hashgrid_main4_kernel(
    const float* __restrict__ x,
    const float4* __restrict__ ws4,
    float* __restrict__ out,           // [BATCH*24] floats
    int quarter)                       // total/4, divisible by 6
{
    int t = blockIdx.x * 256 + threadIdx.x;
    if (t >= quarter) return;

    int b = t / LP;
    int p = t - b * LP;

    const int l0 = 2 * p, l1 = l0 + 1;
    const float res0 = (float)(16 << l0);   // exact for these params
    const float res1 = (float)(16 << l1);
    const float4* __restrict__ g0 = ws4 + l0 * HASH_SIZE;
    const float4* __restrict__ g1 = ws4 + l1 * HASH_SIZE;
    const int bq = quarter / LP;            // batch/4

    // ---- load + clamp the 4 x-values (coalesced/broadcast) ----
    float xc0 = fminf(fmaxf(x[b          ], 0.0f), 1.0f);
    float xc1 = fminf(fmaxf(x[b +     bq ], 0.0f), 1.0f);
    float xc2 = fminf(fmaxf(x[b + 2 * bq ], 0.0f), 1.0f);
    float xc3 = fminf(fmaxf(x[b + 3 * bq ], 0.0f), 1.0f);

    // ---- indices & weights for all 4 points x 2 levels ----
    float pA0 = xc0 * res0, pB0 = xc0 * res1;
    float pA1 = xc1 * res0, pB1 = xc1 * res1;
    float pA2 = xc2 * res0, pB2 = xc2 * res1;
    float pA3 = xc3 * res0, pB3 = xc3 * res1;

    float fA0 = floorf(pA0), fB0 = floorf(pB0);
    float fA1 = floorf(pA1), fB1 = floorf(pB1);
    float fA2 = floorf(pA2), fB2 = floorf(pB2);
    float fA3 = floorf(pA3), fB3 = floorf(pB3);

    float wA0 = pA0 - fA0, wB0 = pB0 - fB0;
    float wA1 = pA1 - fA1, wB1 = pB1 - fB1;
    float wA2 = pA2 - fA2, wB2 = pB2 - fB2;
    float wA3 = pA3 - fA3, wB3 = pB3 - fB3;

    int hA0 = ((int)fA0) & (HASH_SIZE - 1), hB0 = ((int)fB0) & (HASH_SIZE - 1);
    int hA1 = ((int)fA1) & (HASH_SIZE - 1), hB1 = ((int)fB1) & (HASH_SIZE - 1);
    int hA2 = ((int)fA2) & (HASH_SIZE - 1), hB2 = ((int)fB2) & (HASH_SIZE - 1);
    int hA3 = ((int)fA3) & (HASH_SIZE - 1), hB3 = ((int)fB3) & (HASH_SIZE - 1);

    // ---- issue all 8 gathers back-to-back (max outstanding misses) ----
    float4 eA0 = g0[hA0];
    float4 eB0 = g1[hB0];
    float4 eA1 = g0[hA1];
    float4 eB1 = g1[hB1];
    float4 eA2 = g0[hA2];
    float4 eB2 = g1[hB2];
    float4 eA3 = g0[hA3];
    float4 eB3 = g1[hB3];

    // ---- interpolate + 4 nontemporal coalesced stores ----
    floatx4* out4 = reinterpret_cast<floatx4*>(out);
    floatx4 r;

    r.x = (1.0f - wA0) * eA0.x + wA0 * eA0.z;
    r.y = (1.0f - wA0) * eA0.y + wA0 * eA0.w;
    r.z = (1.0f - wB0) * eB0.x + wB0 * eB0.z;
    r.w = (1.0f - wB0) * eB0.y + wB0 * eB0.w;
    __builtin_nontemporal_store(r, out4 + t);

    r.x = (1.0f - wA1) * eA1.x + wA1 * eA1.z;
    r.y = (1.0f - wA1) * eA1.y + wA1 * eA1.w;
    r.z = (1.0f - wB1) * eB1.x + wB1 * eB1.z;
    r.w = (1.0f - wB1) * eB1.y + wB1 * eB1.w;
    __builtin_nontemporal_store(r, out4 + t + quarter);

    r.x = (1.0f - wA2) * eA2.x + wA2 * eA2.z;
    r.y = (1.0f - wA2) * eA2.y + wA2 * eA2.w;
    r.z = (1.0f - wB2) * eB2.x + wB2 * eB2.z;
    r.w = (1.0f - wB2) * eB2.y + wB2 * eB2.w;
    __builtin_nontemporal_store(r, out4 + t + 2 * quarter);

    r.x = (1.0f - wA3) * eA3.x + wA3 * eA3.z;
    r.y = (1.0f - wA3) * eA3.y + wA3 * eA3.w;
    r.z = (1.0f - wB3) * eB3.x + wB3 * eB3.z;
    r.w = (1.0f - wB3) * eB3.y + wB3 * eB3.w;
    __builtin_nontemporal_store(r, out4 + t + 3 * quarter);
}

// ---------------------------------------------------------------------------
// Generic pair kernel (round-5 structure) for batch % 4 != 0.
// ---------------------------------------------------------------------------
__global__ __launch_bounds__(256) void hashgrid_pair_kernel(
    const float* __restrict__ x,
    const float4* __restrict__ ws4,
    float* __restrict__ out,
    int total)                         // BATCH * 6
{
    int t = blockIdx.x * 256 + threadIdx.x;
    if (t >= total) return;
    int b = t / LP;
    int p = t - b * LP;
    float xc = fminf(fmaxf(x[b], 0.0f), 1.0f);

    floatx4 r;
    #pragma unroll
    for (int k = 0; k < 2; ++k) {
        int   lvl = p * 2 + k;
        float res = (float)(16 << lvl);
        float pos = xc * res;
        float fi  = floorf(pos);
        float w   = pos - fi;
        int   h0  = ((int)fi) & (HASH_SIZE - 1);
        float4 e = ws4[lvl * HASH_SIZE + h0];
        float omw = 1.0f - w;
        float r0 = omw * e.x + w * e.z;
        float r1 = omw * e.y + w * e.w;
        if (k == 0) { r.x = r0; r.y = r1; }
        else        { r.z = r0; r.w = r1; }
    }
    __builtin_nontemporal_store(r, reinterpret_cast<floatx4*>(out) + t);
}

// ---------------------------------------------------------------------------
// Fallback (ws too small): direct kernel, known-correct.
// ---------------------------------------------------------------------------
__global__ __launch_bounds__(256) void hashgrid_direct_kernel(
    const float* __restrict__ x,
    const float* __restrict__ table,
    float* __restrict__ out,
    int total)
{
    int idx = blockIdx.x * blockDim.x + threadIdx.x;
    if (idx >= total) return;
    int b = idx / N_LEVELS;
    int l = idx - b * N_LEVELS;
    float xc  = fminf(fmaxf(x[b], 0.0f), 1.0f);
    float res = (float)(16 << l);
    float pos = xc * res;
    float fi  = floorf(pos);
    int   i0  = (int)fi;
    float w   = pos - fi;
    int h0 = i0 & (HASH_SIZE - 1);
    int h1 = (i0 + 1) & (HASH_SIZE - 1);
    const float2 e0 = *reinterpret_cast<const float2*>(table + h0 * (N_LEVELS * 2) + l * 2);
    const float2 e1 = *reinterpret_cast<const float2*>(table + h1 * (N_LEVELS * 2) + l * 2);
    float omw = 1.0f - w;
    float2 rr;
    rr.x = omw * e0.x + w * e1.x;
    rr.y = omw * e0.y + w * e1.y;
    *reinterpret_cast<float2*>(out + (size_t)idx * 2) = rr;
}

extern "C" void kernel_launch(void* const* d_in, const int* in_sizes, int n_in,
                              void* d_out, int out_size, void* d_ws, size_t ws_size,
                              hipStream_t stream) {
    const float* x     = (const float*)d_in[0];
    const float* table = (const float*)d_in[1];
    int batch = in_sizes[0];

    const size_t ws_needed = (size_t)N_LEVELS * HASH_SIZE * sizeof(float4);  // 3 MB

    if (ws_size >= ws_needed) {
        float4* ws4 = (float4*)d_ws;

        int ta = N_LEVELS * HASH_SIZE;
        build_ws_kernel<<<(ta + 255) / 256, 256, 0, stream>>>(table, ws4);

        int total = batch * LP;                    // BATCH * 6
        if ((batch & 3) == 0) {
            int quarter = total >> 2;              // divisible by 6 (batch%4==0)
            hashgrid_main4_kernel<<<(quarter + 255) / 256, 256, 0, stream>>>(
                x, ws4, (float*)d_out, quarter);
        } else {
            hashgrid_pair_kernel<<<(total + 255) / 256, 256, 0, stream>>>(
                x, ws4, (float*)d_out, total);
        }
    } else {
        int total = batch * N_LEVELS;
        hashgrid_direct_kernel<<<(total + 255) / 256, 256, 0, stream>>>(
            x, table, (float*)d_out, total);
    }
}